// Round 4
// baseline (2437.053 us; speedup 1.0000x reference)
//
#include <hip/hip_runtime.h>
#include <hip/hip_cooperative_groups.h>
#include <math.h>

namespace cg = cooperative_groups;

#define NN 20000
#define NPAD 20096          // padded rows for unguarded MFMA staging (157*128)
#define CC 256
#define HH 8
#define EE 160000
#define TE 320000
#define KVSTRIDE 512        // bytes per kv row: interleaved per-lane [k 8B | v 8B] x 32
#define APAN ((size_t)NPAD*32)   // u16 elems per A-operand k-panel (xbf/hbf/A2)
#define BPAN 40960               // u16 elems per Wt5 k-panel (1280*32)
#define OPAN 8192                // u16 elems per Wto k-panel (256*32)

typedef unsigned short u16;
typedef unsigned char u8;
typedef __attribute__((ext_vector_type(8))) short bf16x8;
typedef __attribute__((ext_vector_type(4))) float f32x4;
typedef __attribute__((ext_vector_type(2))) float f32x2;

__device__ __forceinline__ float gelu_exact(float x){
    return 0.5f*x*(1.0f+erff(x*0.7071067811865476f));
}
__device__ __forceinline__ u16 f2bf(float f){
    unsigned u = __float_as_uint(f);
    unsigned r = (u + 0x7fffu + ((u >> 16) & 1u)) >> 16;
    return (u16)r;
}
__device__ __forceinline__ void dec8(uint4 u, float* f){
    f[0]=__uint_as_float(u.x<<16); f[1]=__uint_as_float(u.x&0xffff0000u);
    f[2]=__uint_as_float(u.y<<16); f[3]=__uint_as_float(u.y&0xffff0000u);
    f[4]=__uint_as_float(u.z<<16); f[5]=__uint_as_float(u.z&0xffff0000u);
    f[6]=__uint_as_float(u.w<<16); f[7]=__uint_as_float(u.w&0xffff0000u);
}
__device__ __forceinline__ void dec8_fp8u(unsigned lo, unsigned hi, float* f){
    f32x2 a = __builtin_amdgcn_cvt_pk_f32_fp8(lo, false);
    f32x2 b = __builtin_amdgcn_cvt_pk_f32_fp8(lo, true);
    f32x2 c = __builtin_amdgcn_cvt_pk_f32_fp8(hi, false);
    f32x2 d = __builtin_amdgcn_cvt_pk_f32_fp8(hi, true);
    f[0]=a.x; f[1]=a.y; f[2]=b.x; f[3]=b.y;
    f[4]=c.x; f[5]=c.y; f[6]=d.x; f[7]=d.y;
}
__device__ __forceinline__ uint2 enc8_fp8(const float* f){
    int t0 = __builtin_amdgcn_cvt_pk_fp8_f32(f[0], f[1], 0, false);
    t0     = __builtin_amdgcn_cvt_pk_fp8_f32(f[2], f[3], t0, true);
    int t1 = __builtin_amdgcn_cvt_pk_fp8_f32(f[4], f[5], 0, false);
    t1     = __builtin_amdgcn_cvt_pk_fp8_f32(f[6], f[7], t1, true);
    uint2 r; r.x = (unsigned)t0; r.y = (unsigned)t1;
    return r;
}
__device__ __forceinline__ float dot8(const float* a, const float* b){
    return a[0]*b[0]+a[1]*b[1]+a[2]*b[2]+a[3]*b[3]
          +a[4]*b[4]+a[5]*b[5]+a[6]*b[6]+a[7]*b[7];
}
__device__ __forceinline__ void gload_lds16(const u16* gsrc, u16* lds_dst){
    __builtin_amdgcn_global_load_lds((const __attribute__((address_space(1))) unsigned int*)gsrc,
                                     (__attribute__((address_space(3))) unsigned int*)lds_dst,
                                     16, 0, 0);
}

// ======================= CSR build =======================
__global__ void hist_k(const int* __restrict__ ei0, const int* __restrict__ ei1,
                       int* __restrict__ cnt){
    int e = blockIdx.x*256 + threadIdx.x;
    if (e < TE){
        int dst = (e < EE) ? ei0[EE + e] : ei1[EE + (e - EE)];
        atomicAdd(&cnt[dst], 1);
    }
}
__global__ void scan_block_k(const int* __restrict__ cnt, int* __restrict__ incl,
                             int* __restrict__ bsum){
    __shared__ int tmp[256];
    int tid = threadIdx.x;
    int i = blockIdx.x*256 + tid;
    int v = (i < NN) ? cnt[i] : 0;
    tmp[tid] = v;
    __syncthreads();
    for (int d=1; d<256; d<<=1){
        int t = (tid>=d) ? tmp[tid-d] : 0;
        __syncthreads();
        tmp[tid] += t;
        __syncthreads();
    }
    if (i < NN) incl[i] = tmp[tid];
    if (tid == 255) bsum[blockIdx.x] = tmp[255];
}
// per-block bsum prefix computed in-kernel (wave butterfly)
__global__ void finalize_rowptr_k(const int* __restrict__ cnt, const int* __restrict__ incl,
                                  const int* __restrict__ bsum, int* __restrict__ row_ptr){
    __shared__ int pre_s;
    int tid = threadIdx.x;
    if (tid < 64){
        int b = blockIdx.x;
        int v = (tid < b ? bsum[tid] : 0) + (tid + 64 < b ? bsum[tid + 64] : 0);
        #pragma unroll
        for (int d=1; d<64; d<<=1) v += __shfl_xor(v, d);
        if (tid == 0) pre_s = v;
    }
    __syncthreads();
    int i = blockIdx.x*256 + tid;
    if (i < NN) row_ptr[i] = incl[i] - cnt[i] + pre_s;
    if (i == NN) row_ptr[NN] = TE;
}
// stores the final kv-row index rel*NN+src per CSR slot
__global__ void scatter_k(const int* __restrict__ ei0, const int* __restrict__ ei1,
                          const int* __restrict__ row_ptr, int* __restrict__ cursor,
                          int* __restrict__ epk){
    int e = blockIdx.x*256 + threadIdx.x;
    if (e < TE){
        int src, dst, rel;
        if (e < EE){ src = ei0[e]; dst = ei0[EE+e]; rel = 0; }
        else { int ee=e-EE; src = ei1[ee]; dst = ei1[EE+ee]; rel = 1; }
        int pos = atomicAdd(&cursor[dst], 1);
        epk[row_ptr[dst] + pos] = rel*NN + src;
    }
}

// ======================= fused weight/input prep (one dispatch) =======================
// blocks [0,5120): Wt5 k-panels; [5120,7620): cvt x->xbf panels;
// [7620,8644): Wto k-panels; [8644,8664): bias5+sc5; [8664,8704): zero cnt+cursor
// sc5 for k-outputs folds prel/sqrt(DH) * log2(e): attention runs in log2 domain.
__global__ void prep_k(const float* __restrict__ kqv_w, const float* __restrict__ kqv_b,
                       const float* __restrict__ krel, const float* __restrict__ vrel,
                       const float* __restrict__ prel, const float* __restrict__ out_w,
                       const float* __restrict__ x,
                       u16* __restrict__ Wt, u16* __restrict__ xbf, u16* __restrict__ Wto,
                       float* __restrict__ bias5, float* __restrict__ sc5,
                       int* __restrict__ cnt, int* __restrict__ cursor){
    int b = blockIdx.x;
    if (b < 5120){
        int idx = b*256 + threadIdx.x;                 // 4*1280*256
        int k = idx & 255;
        int n = (idx >> 8) % 1280;
        int l = idx / (1280*256);
        const float* W = kqv_w + (size_t)l*196608;     // [256][768]
        float val;
        if (n < 256){
            val = W[k*768 + 256 + n];
        } else {
            int g = (n-256) >> 8;
            int r = g & 1, isv = g >> 1;
            int c = (n-256) & 255;
            int h = c >> 5, f = c & 31;
            const float* Rm = (isv ? vrel : krel) + ((size_t)l*2 + r)*8192 + h*1024;
            int base = isv ? 512 : 0;
            const float4* Wr = (const float4*)(W + k*768 + base + h*32);
            float a = 0.f;
            #pragma unroll
            for (int d4=0; d4<8; ++d4){
                float4 wv = Wr[d4];
                a += wv.x*Rm[(d4*4+0)*32 + f];
                a += wv.y*Rm[(d4*4+1)*32 + f];
                a += wv.z*Rm[(d4*4+2)*32 + f];
                a += wv.w*Rm[(d4*4+3)*32 + f];
            }
            val = a;
        }
        Wt[(size_t)l*327680 + (size_t)(k>>5)*BPAN + n*32 + (k&31)] = f2bf(val);
    } else if (b < 7620){
        int idx = (b-5120)*256 + threadIdx.x;          // 640000 (8 elems each)
        int e = idx*8;
        int row = e >> 8, col = e & 255;
        const float4* xp = (const float4*)x;
        float4 a = xp[(size_t)idx*2], bb = xp[(size_t)idx*2+1];
        uint4 o;
        o.x = (unsigned)f2bf(a.x) | ((unsigned)f2bf(a.y)<<16);
        o.y = (unsigned)f2bf(a.z) | ((unsigned)f2bf(a.w)<<16);
        o.z = (unsigned)f2bf(bb.x) | ((unsigned)f2bf(bb.y)<<16);
        o.w = (unsigned)f2bf(bb.z) | ((unsigned)f2bf(bb.w)<<16);
        *(uint4*)&xbf[(size_t)(col>>5)*APAN + (size_t)row*32 + (col&31)] = o;
    } else if (b < 8644){
        int idx = (b-7620)*256 + threadIdx.x;          // 4*256*256
        int k = idx & 255;
        int n = (idx >> 8) & 255;
        int l = idx >> 16;
        Wto[(size_t)l*65536 + (size_t)(k>>5)*OPAN + n*32 + (k&31)] =
            f2bf(out_w[(size_t)l*65536 + k*256 + n]);
    } else if (b < 8664){
        int idx = (b-8644)*256 + threadIdx.x;          // 4*1280
        if (idx >= 4*1280) return;
        int n = idx % 1280, l = idx / 1280;
        const float* B = kqv_b + l*768;
        float val, scl = 1.f;
        if (n < 256) val = B[256+n];
        else {
            int g = (n-256) >> 8;
            int r = g & 1, isv = g >> 1;
            int c = (n-256) & 255;
            int h = c >> 5, f = c & 31;
            const float* Rm = (isv ? vrel : krel) + ((size_t)l*2 + r)*8192 + h*1024;
            int base = isv ? 512 : 0;
            float a = 0.f;
            for (int d=0; d<32; ++d) a += B[base + h*32 + d] * Rm[d*32 + f];
            val = a;
            // prel / sqrt(DH) * log2(e): logits computed in log2 domain downstream
            if (!isv) scl = prel[l*16 + r*8 + h] * (0.17677669529663687f * 1.4426950408889634f);
        }
        bias5[idx] = val;
        sc5[idx] = scl;
    } else {
        // zero cnt + cursor (replaces hipMemsetAsync dispatch)
        int t = (b-8664)*256 + threadIdx.x;            // [0,10240)
        for (int j = t; j < NN; j += 10240){ cnt[j] = 0; cursor[j] = 0; }
    }
}

// ======================= phase bodies (verbatim R2 kernels, smem passed in) ==========

// K1: 5-output MFMA GEMM, pipelined dbuf. smem usage: 33792 B.
__device__ __forceinline__ void gemm5_body(int L, const u16* __restrict__ A,
        const u16* __restrict__ Wt, const float* __restrict__ biasp,
        const float* __restrict__ sc5p,
        u16* __restrict__ qb, u8* __restrict__ kvb, char* smem){
    int xcd = L & 7;
    int t = L >> 3;                  // 0..199
    int ytile = xcd*20 + t/10;       // 0..159
    int xtile = t % 10;
    if (ytile >= 157) return;        // uniform per block (before any barrier)
    int col0 = xtile * 128;
    int row0 = ytile * 128;

    u16* As = (u16*)smem;                        // 2 buffers of 4096 u16
    u16* Bs = (u16*)(smem + 16384);              // 2 buffers of 4096 u16
    float* Cs = (float*)smem;                    // 128*66 (aliases As/Bs post-K-loop)
    int tid = threadIdx.x;
    int w = tid >> 6, lane = tid & 63;
    int wm = w & 1, wn = w >> 1;
    f32x4 acc[4][4];
    #pragma unroll
    for (int i=0;i<4;++i)
        #pragma unroll
        for (int j=0;j<4;++j) acc[i][j] = (f32x4){0.f,0.f,0.f,0.f};

    int lm = lane & 15, quad = lane >> 4;
    int kq0 = quad ^ (lm & 3);
    int aoff = (wm*64 + lm)*32 + kq0*8;
    int boff = (wn*64 + lm)*32 + kq0*8;

    auto stage5 = [&](int pan, int buf){
        #pragma unroll
        for (int it = 0; it < 2; ++it){
            int s = it*256 + tid;              // 16B slot id (0..511)
            int row = s >> 2, q0 = s & 3;
            int kq = q0 ^ (row & 3);           // write-side swizzle via source addr
            gload_lds16(&A [(size_t)pan*APAN + (size_t)(row0+row)*32 + kq*8],
                        &As[(size_t)buf*4096 + (size_t)s*8]);
            gload_lds16(&Wt[(size_t)pan*BPAN + (size_t)(col0+row)*32 + kq*8],
                        &Bs[(size_t)buf*4096 + (size_t)s*8]);
        }
    };

    stage5(0, 0);
    __syncthreads();
    #pragma unroll
    for (int pan = 0; pan < 8; ++pan){
        int cur = pan & 1;
        if (pan < 7) stage5(pan+1, cur^1);     // in flight across the compute below
        bf16x8 af[4], bfr[4];
        #pragma unroll
        for (int mi=0; mi<4; ++mi) af[mi]  = *(bf16x8*)&As[cur*4096 + aoff + mi*512];
        #pragma unroll
        for (int ni=0; ni<4; ++ni) bfr[ni] = *(bf16x8*)&Bs[cur*4096 + boff + ni*512];
        #pragma unroll
        for (int mi=0; mi<4; ++mi)
            #pragma unroll
            for (int ni=0; ni<4; ++ni)
                acc[mi][ni] = __builtin_amdgcn_mfma_f32_16x16x32_bf16(af[mi], bfr[ni], acc[mi][ni], 0,0,0);
        __syncthreads();    // drains vmcnt(0); also fences Cs aliasing after last pan
    }

    int bufi = col0 >> 8;   // 0:q 1:kr0 2:kr1 3:vr0 4:vr1 (uniform per block)
    int cbase = col0 & 255;
    float bvv[4], scv[4];
    #pragma unroll
    for (int ni=0; ni<4; ++ni){
        bvv[ni] = biasp[col0 + wn*64 + ni*16 + lm];
        scv[ni] = sc5p [col0 + wn*64 + ni*16 + lm];
    }

    int rowl_s = tid >> 3;              // 0..31
    int col8   = tid & 7;               // 0..7 (8 lcols each)
    int gcb    = (col8 >> 2)*64 + (col8 & 3)*8;

    #pragma unroll
    for (int p=0; p<2; ++p){
        if (p) __syncthreads();
        #pragma unroll
        for (int nj=0; nj<2; ++nj){
            int ni = p*2 + nj;
            int lcol = wn*32 + nj*16 + lm;
            #pragma unroll
            for (int mi=0; mi<4; ++mi){
                #pragma unroll
                for (int t2=0; t2<4; ++t2){
                    int lr = wm*64 + mi*16 + quad*4 + t2;
                    Cs[lr*66 + lcol] = (acc[mi][ni][t2] + bvv[ni]) * scv[ni];
                }
            }
        }
        __syncthreads();
        int cw = cbase + gcb + p*32;
        #pragma unroll
        for (int it=0; it<4; ++it){
            int rl = rowl_s + it*32;
            int r = row0 + rl;
            if (r < NN){
                const float* src = &Cs[rl*66 + col8*8];
                float cf[8];
                *(float4*)&cf[0] = *(const float4*)&src[0];
                *(float4*)&cf[4] = *(const float4*)&src[4];
                if (bufi == 0){
                    uint4 o;
                    o.x = (unsigned)f2bf(cf[0]) | ((unsigned)f2bf(cf[1])<<16);
                    o.y = (unsigned)f2bf(cf[2]) | ((unsigned)f2bf(cf[3])<<16);
                    o.z = (unsigned)f2bf(cf[4]) | ((unsigned)f2bf(cf[5])<<16);
                    o.w = (unsigned)f2bf(cf[6]) | ((unsigned)f2bf(cf[7])<<16);
                    *(uint4*)&qb[(size_t)r*256 + cw] = o;
                } else if (bufi <= 2){
                    int rel = bufi - 1;
                    uint2 o = enc8_fp8(cf);
                    *(uint2*)&kvb[(size_t)(rel*NN + r)*KVSTRIDE + (size_t)cw*2] = o;
                } else {
                    int rel = bufi - 3;
                    uint2 o = enc8_fp8(cf);
                    *(uint2*)&kvb[(size_t)(rel*NN + r)*KVSTRIDE + (size_t)cw*2 + 8] = o;
                }
            }
        }
    }
}

// K2: split-wave CSR attention, online softmax (log2 domain), one node per wave.
__device__ __forceinline__ void attn_body(int node, const u16* __restrict__ qb,
        const u8* __restrict__ kvb,
        const int* __restrict__ row_ptr, const int* __restrict__ epk,
        u16* __restrict__ A2){
    int lane = threadIdx.x & 63;
    int l32 = lane & 31;
    int half = lane >> 5;
    int start = row_ptr[node], end = row_ptr[node+1];
    float qf[8];
    {
        uint4 qr = *(const uint4*)&qb[(size_t)node*256 + l32*8];
        dec8(qr, qf);
    }
    float m = -1e30f, s = 0.f;
    float acc[8] = {0.f,0.f,0.f,0.f,0.f,0.f,0.f,0.f};

    int i0 = start + half;
    uint4 kv0 = {0,0,0,0}, kv1 = {0,0,0,0}, kv2 = {0,0,0,0}, kv3 = {0,0,0,0};
    if (i0     < end) kv0 = *(const uint4*)(&kvb[(size_t)epk[i0  ]*KVSTRIDE] + l32*16);
    if (i0 + 2 < end) kv1 = *(const uint4*)(&kvb[(size_t)epk[i0+2]*KVSTRIDE] + l32*16);
    if (i0 + 4 < end) kv2 = *(const uint4*)(&kvb[(size_t)epk[i0+4]*KVSTRIDE] + l32*16);
    if (i0 + 6 < end) kv3 = *(const uint4*)(&kvb[(size_t)epk[i0+6]*KVSTRIDE] + l32*16);
    int pk0 = (i0 + 8  < end) ? epk[i0+8]  : 0;
    int pk1 = (i0 + 10 < end) ? epk[i0+10] : 0;

    for (int i = i0; i < end; i += 4){
        uint4 ca = kv0, cb = kv1;
        kv0 = kv2; kv1 = kv3;
        if (i + 8  < end) kv2 = *(const uint4*)(&kvb[(size_t)pk0*KVSTRIDE] + l32*16);
        if (i + 10 < end) kv3 = *(const uint4*)(&kvb[(size_t)pk1*KVSTRIDE] + l32*16);
        if (i + 12 < end) pk0 = epk[i+12];
        if (i + 14 < end) pk1 = epk[i+14];

        float kfa[8], kfb[8];
        dec8_fp8u(ca.x, ca.y, kfa);
        dec8_fp8u(cb.x, cb.y, kfb);
        float p0 = dot8(qf, kfa);
        float p1 = dot8(qf, kfb);
        p0 += __shfl_xor(p0, 1);  p1 += __shfl_xor(p1, 1);
        p0 += __shfl_xor(p0, 2);  p1 += __shfl_xor(p1, 2);   // per-head log2-logit
        if (i + 2 >= end) p1 = -1e30f;                       // second slot invalid
        float mo = m;
        m = fmaxf(fmaxf(m, p0), p1);                         // v_max3
        float sc  = __builtin_amdgcn_exp2f(mo - m);
        float pe0 = __builtin_amdgcn_exp2f(p0 - m);
        float pe1 = __builtin_amdgcn_exp2f(p1 - m);
        s = s*sc + (pe0 + pe1);
        float va[8], vb[8];
        dec8_fp8u(ca.z, ca.w, va);
        dec8_fp8u(cb.z, cb.w, vb);
        #pragma unroll
        for (int j=0;j<8;++j) acc[j] = acc[j]*sc + (pe0*va[j] + pe1*vb[j]);
    }
    // merge the two halves' online-softmax states (m=-1e30: no inf-inf NaN)
    float mO = __shfl_xor(m, 32);
    float mA = fmaxf(m, mO);
    float eS = __builtin_amdgcn_exp2f(m - mA);
    float sh = s * eS;
    float sA = sh + __shfl_xor(sh, 32);
    float rs = 1.f / fmaxf(sA, 1e-16f);
    float oA[8];
    #pragma unroll
    for (int j=0;j<8;++j){
        float a = acc[j] * eS;
        oA[j] = a + __shfl_xor(a, 32);
    }
    if (half == 0){
        u16 o[8];
        #pragma unroll
        for (int j=0;j<8;++j) o[j] = f2bf(gelu_exact(oA[j]*rs));
        uint4 ov;
        ov.x = (unsigned)o[0] | ((unsigned)o[1]<<16);
        ov.y = (unsigned)o[2] | ((unsigned)o[3]<<16);
        ov.z = (unsigned)o[4] | ((unsigned)o[5]<<16);
        ov.w = (unsigned)o[6] | ((unsigned)o[7]<<16);
        int c0 = l32*8;
        *(uint4*)&A2[(size_t)(c0>>5)*APAN + (size_t)node*32 + (c0&31)] = ov;
    }
}

// K3a: out GEMM + skip + relu + LN. smem: As 4KB + Bs 16KB + parts ~3KB = 23.5KB.
__device__ __forceinline__ void gemmOln_body(int vb, const u16* __restrict__ A,
        const u16* __restrict__ Wt, const float* __restrict__ bias,
        const float* __restrict__ h_in, float sskip,
        const float* __restrict__ g, const float* __restrict__ b,
        float* __restrict__ h_out, u16* __restrict__ hbf, char* smem){
    u16* As = (u16*)smem;                      // 2048 u16
    u16* Bs = (u16*)(smem + 4096);             // 8192 u16
    float* part_s = (float*)(smem + 4096 + 16384);   // 64*2
    float* part_q = part_s + 128;
    float* mu_s   = part_q + 128;
    float* rstd_s = mu_s + 64;
    int tid = threadIdx.x;
    int w = tid >> 6, lane = tid & 63;
    int row0 = vb * 64;
    int wm = w & 1, wn = w >> 1;
    f32x4 acc[2][8];
    #pragma unroll
    for (int i=0;i<2;++i)
        #pragma unroll
        for (int j=0;j<8;++j) acc[i][j] = (f32x4){0.f,0.f,0.f,0.f};

    int lm = lane & 15, quad = lane >> 4;
    int kq0 = quad ^ (lm & 3);
    int aoff = (wm*32 + lm)*32 + kq0*8;
    int boff = (wn*128 + lm)*32 + kq0*8;

    for (int kk = 0; kk < 8; ++kk){
        {
            int s = tid;                       // 256 slots = 64 rows x 4
            int row = s >> 2, q0 = s & 3;
            int kq = q0 ^ (row & 3);
            gload_lds16(&A[(size_t)kk*APAN + (size_t)(row0+row)*32 + kq*8],
                        &As[(size_t)(w*64)*8]);
        }
        #pragma unroll
        for (int it = 0; it < 4; ++it){        // 1024 slots = 256 n-rows x 4
            int s = it*256 + tid;
            int row = s >> 2, q0 = s & 3;
            int kq = q0 ^ (row & 3);
            gload_lds16(&Wt[(size_t)kk*OPAN + (size_t)row*32 + kq*8],
                        &Bs[(size_t)(it*256 + w*64)*8]);
        }
        __syncthreads();
        bf16x8 af[2], bfr[8];
        #pragma unroll
        for (int mi=0; mi<2; ++mi) af[mi]  = *(bf16x8*)&As[aoff + mi*512];
        #pragma unroll
        for (int ni=0; ni<8; ++ni) bfr[ni] = *(bf16x8*)&Bs[boff + ni*512];
        #pragma unroll
        for (int mi=0; mi<2; ++mi)
            #pragma unroll
            for (int ni=0; ni<8; ++ni)
                acc[mi][ni] = __builtin_amdgcn_mfma_f32_16x16x32_bf16(af[mi], bfr[ni], acc[mi][ni], 0,0,0);
        __syncthreads();
    }

    float osk = 1.f - sskip;
    float bv[8], gv[8], bbv[8];
    #pragma unroll
    for (int ni=0; ni<8; ++ni){
        int colg = wn*128 + ni*16 + lm;
        bv[ni]  = bias[colg];
        gv[ni]  = g[colg];
        bbv[ni] = b[colg];
    }
    #pragma unroll
    for (int mi=0; mi<2; ++mi){
        #pragma unroll
        for (int t=0; t<4; ++t){
            int lr = wm*32 + mi*16 + quad*4 + t;
            int r = row0 + lr;
            float ps = 0.f, pq = 0.f;
            #pragma unroll
            for (int ni=0; ni<8; ++ni){
                int colg = wn*128 + ni*16 + lm;
                float hv = (r < NN) ? h_in[(size_t)r*256 + colg] : 0.f;
                float val = sskip*(acc[mi][ni][t] + bv[ni]) + osk*hv;
                val = fmaxf(val, 0.f);
                acc[mi][ni][t] = val;
                ps += val; pq += val*val;
            }
            // reduce over the 16 lm lanes of this quad-group
            ps += __shfl_xor(ps, 1); pq += __shfl_xor(pq, 1);
            ps += __shfl_xor(ps, 2); pq += __shfl_xor(pq, 2);
            ps += __shfl_xor(ps, 4); pq += __shfl_xor(pq, 4);
            ps += __shfl_xor(ps, 8); pq += __shfl_xor(pq, 8);
            if (lm == 0){
                part_s[lr*2 + wn] = ps;
                part_q[lr*2 + wn] = pq;
            }
        }
    }
    __syncthreads();
    if (tid < 64){
        float S = part_s[tid*2] + part_s[tid*2+1];
        float Q = part_q[tid*2] + part_q[tid*2+1];
        float mu = S * (1.f/256.f);
        float var = Q * (1.f/256.f) - mu*mu;
        mu_s[tid] = mu;
        rstd_s[tid] = rsqrtf(var + 1e-5f);
    }
    __syncthreads();
    #pragma unroll
    for (int mi=0; mi<2; ++mi){
        #pragma unroll
        for (int t=0; t<4; ++t){
            int lr = wm*32 + mi*16 + quad*4 + t;
            int r = row0 + lr;
            if (r >= NN) continue;
            float mu = mu_s[lr], rstd = rstd_s[lr];
            #pragma unroll
            for (int ni=0; ni<8; ++ni){
                int colg = wn*128 + ni*16 + lm;
                float o = (acc[mi][ni][t] - mu)*rstd*gv[ni] + bbv[ni];
                h_out[(size_t)r*256 + colg] = o;
                hbf[(size_t)(colg>>5)*APAN + (size_t)r*32 + (colg&31)] = f2bf(o);
            }
        }
    }
}

// K3b: out GEMM + skip blend (final layer). smem: As/Bs dbuf 16+16 = 32KB.
__device__ __forceinline__ void gemmO_body(int vb, const u16* __restrict__ A,
        const u16* __restrict__ Wt, const float* __restrict__ bias,
        const float* __restrict__ h_in, float sskip, float* __restrict__ outp,
        char* smem){
    u16* As = (u16*)smem;                 // 2 buffers x 4096
    u16* Bs = (u16*)(smem + 16384);       // 2 buffers x 4096
    int tid = threadIdx.x;
    int w = tid >> 6, lane = tid & 63;
    int row0 = (vb % 157) * 128;
    int col0 = (vb / 157) * 128;
    int wm = w & 1, wn = w >> 1;
    f32x4 acc[4][4];
    #pragma unroll
    for (int i=0;i<4;++i)
        #pragma unroll
        for (int j=0;j<4;++j) acc[i][j] = (f32x4){0.f,0.f,0.f,0.f};

    int lm = lane & 15, quad = lane >> 4;
    int kq0 = quad ^ (lm & 3);
    int aoff = (wm*64 + lm)*32 + kq0*8;
    int boff = (wn*64 + lm)*32 + kq0*8;

    auto stageF = [&](int kk, int buf){
        #pragma unroll
        for (int it = 0; it < 2; ++it){
            int s = it*256 + tid;
            int row = s >> 2, q0 = s & 3;
            int kq = q0 ^ (row & 3);
            gload_lds16(&A [(size_t)kk*APAN + (size_t)(row0+row)*32 + kq*8],
                        &As[(size_t)buf*4096 + (size_t)s*8]);
            gload_lds16(&Wt[(size_t)kk*OPAN + (size_t)(col0+row)*32 + kq*8],
                        &Bs[(size_t)buf*4096 + (size_t)s*8]);
        }
    };

    stageF(0, 0);
    __syncthreads();
    #pragma unroll
    for (int kk = 0; kk < 8; ++kk){
        int cur = kk & 1;
        if (kk < 7) stageF(kk+1, cur^1);
        bf16x8 af[4], bfr[4];
        #pragma unroll
        for (int mi=0; mi<4; ++mi) af[mi]  = *(bf16x8*)&As[cur*4096 + aoff + mi*512];
        #pragma unroll
        for (int ni=0; ni<4; ++ni) bfr[ni] = *(bf16x8*)&Bs[cur*4096 + boff + ni*512];
        #pragma unroll
        for (int mi=0; mi<4; ++mi)
            #pragma unroll
            for (int ni=0; ni<4; ++ni)
                acc[mi][ni] = __builtin_amdgcn_mfma_f32_16x16x32_bf16(af[mi], bfr[ni], acc[mi][ni], 0,0,0);
        __syncthreads();
    }
    float os = 1.f - sskip;
    #pragma unroll
    for (int ni=0; ni<4; ++ni){
        int colg = col0 + wn*64 + ni*16 + lm;
        float bv = bias[colg];
        #pragma unroll
        for (int mi=0; mi<4; ++mi){
            #pragma unroll
            for (int t=0; t<4; ++t){
                int r = row0 + wm*64 + mi*16 + quad*4 + t;
                if (r < NN)
                    outp[(size_t)r*256 + colg] =
                        sskip*(acc[mi][ni][t] + bv) + os*h_in[(size_t)r*256 + colg];
            }
        }
    }
}

// ======================= cooperative 4-layer megakernel =======================
struct CoopArgs {
    const u16* xbf; u16* hbf;
    u16* qb; u8* kvb; u16* A2;
    const int* row_ptr; const int* epk;
    const u16* Wt5; const float* bias5; const float* sc5;
    const u16* Wto; const float* out_b;
    const float* skip; const float* ln_g; const float* ln_b;
    const float* x; float* hA; float* hB; float* outp;
};

__global__ __launch_bounds__(256, 4) void layers_k(CoopArgs a){
    cg::grid_group grid = cg::this_grid();
    __shared__ __align__(16) char smem[33792];

    #pragma unroll 1
    for (int l = 0; l < 4; ++l){
        const u16* Ain  = (l == 0) ? a.xbf : a.hbf;
        const float* h_in = (l == 0) ? a.x : ((l == 1) ? a.hA : ((l == 2) ? a.hB : a.hA));
        float* h_out = (l == 0) ? a.hA : ((l == 1) ? a.hB : a.hA);
        const u16* Wt5l = a.Wt5 + (size_t)l*327680;
        const float* b5l = a.bias5 + l*1280;
        const float* s5l = a.sc5 + l*1280;
        const u16* Wtol = a.Wto + (size_t)l*65536;
        const float* obl = a.out_b + l*256;

        // ---- phase 1: kqv GEMM (1600 virtual blocks; stride % 8 == 0 keeps XCD map) ----
        for (int L = blockIdx.x; L < 1600; L += gridDim.x){
            gemm5_body(L, Ain, Wt5l, b5l, s5l, a.qb, a.kvb, smem);
            __syncthreads();
        }
        __threadfence();
        grid.sync();
        __threadfence();

        // ---- phase 2: attention (one node per wave, grid-strided) ----
        {
            int gw = (blockIdx.x * blockDim.x + threadIdx.x) >> 6;
            int nw = (gridDim.x * blockDim.x) >> 6;
            for (int node = gw; node < NN; node += nw)
                attn_body(node, a.qb, a.kvb, a.row_ptr, a.epk, a.A2);
        }
        __threadfence();
        grid.sync();
        __threadfence();

        // ---- phase 3: out GEMM + epilogue ----
        float sskip = 1.f/(1.f+__expf(-a.skip[l]));
        if (l < 3){
            const float* gl = a.ln_g + l*256;
            const float* bl = a.ln_b + l*256;
            for (int vb = blockIdx.x; vb < 314; vb += gridDim.x){
                gemmOln_body(vb, a.A2, Wtol, obl, h_in, sskip, gl, bl, h_out, a.hbf, smem);
                __syncthreads();
            }
            __threadfence();
            grid.sync();
            __threadfence();
        } else {
            for (int vb = blockIdx.x; vb < 314; vb += gridDim.x){
                gemmO_body(vb, a.A2, Wtol, obl, h_in, sskip, a.outp, smem);
                __syncthreads();
            }
        }
    }
}

// ======================= host =======================
extern "C" void kernel_launch(void* const* d_in, const int* in_sizes, int n_in,
                              void* d_out, int out_size, void* d_ws, size_t ws_size,
                              hipStream_t stream){
    (void)in_sizes; (void)n_in; (void)out_size; (void)ws_size;
    const float* x     = (const float*)d_in[0];
    const int*   ei0   = (const int*)d_in[1];
    const int*   ei1   = (const int*)d_in[2];
    const float* kqv_w = (const float*)d_in[3];
    const float* kqv_b = (const float*)d_in[4];
    const float* out_w = (const float*)d_in[5];
    const float* out_b = (const float*)d_in[6];
    const float* skip  = (const float*)d_in[7];
    const float* krel  = (const float*)d_in[8];
    const float* vrel  = (const float*)d_in[9];
    const float* prel  = (const float*)d_in[10];
    const float* ln_g  = (const float*)d_in[11];
    const float* ln_b  = (const float*)d_in[12];
    float* outp = (float*)d_out;

    char* wp = (char*)d_ws;
    auto alloc = [&](size_t bytes)->void*{
        void* p = wp; wp += (bytes + 255) & ~(size_t)255; return p;
    };
    float* hA    = (float*)alloc((size_t)NN*CC*4);
    float* hB    = (float*)alloc((size_t)NN*CC*4);
    u16*   xbf   = (u16*)alloc((size_t)NPAD*CC*2);   // k-panel layout
    u16*   hbf   = (u16*)alloc((size_t)NPAD*CC*2);   // k-panel layout
    u16*   A2    = (u16*)alloc((size_t)NPAD*CC*2);   // k-panel layout
    u16*   qb    = (u16*)alloc((size_t)NN*CC*2);
    u8*    kvb   = (u8*)alloc((size_t)2*NN*KVSTRIDE);   // [rel*NN+node][lane-interleaved k|v fp8]
    u16*   Wt5   = (u16*)alloc((size_t)4*1280*256*2);   // k-panel layout
    u16*   Wto   = (u16*)alloc((size_t)4*256*256*2);    // k-panel layout
    float* bias5 = (float*)alloc((size_t)4*1280*4);
    float* sc5   = (float*)alloc((size_t)4*1280*4);
    int* cnt     = (int*)alloc((size_t)NN*4);
    int* cursor  = (int*)alloc((size_t)NN*4);
    int* incl    = (int*)alloc((size_t)NN*4);
    int* row_ptr = (int*)alloc((size_t)(NN+1)*4);
    int* bsum    = (int*)alloc(128*4);
    int* epk     = (int*)alloc((size_t)TE*4);

    // fused prep (weights + input cast + cnt/cursor zeroing) — one dispatch
    prep_k<<<8704,256,0,stream>>>(kqv_w, kqv_b, krel, vrel, prel, out_w, x,
                                  Wt5, xbf, Wto, bias5, sc5, cnt, cursor);

    // CSR build
    hist_k<<<1250,256,0,stream>>>(ei0, ei1, cnt);
    scan_block_k<<<79,256,0,stream>>>(cnt, incl, bsum);
    finalize_rowptr_k<<<79,256,0,stream>>>(cnt, incl, bsum, row_ptr);
    scatter_k<<<1250,256,0,stream>>>(ei0, ei1, row_ptr, cursor, epk);

    // cooperative 4-layer megakernel (grid sized for guaranteed co-residency)
    static int coop_blocks = 0;
    if (coop_blocks == 0){
        int nb = 0;
        if (hipOccupancyMaxActiveBlocksPerMultiprocessor(&nb, layers_k, 256, 0) != hipSuccess
            || nb < 1) nb = 1;
        if (nb > 8) nb = 8;
        coop_blocks = nb * 256;     // 256 CUs on MI355X
    }
    CoopArgs ca;
    ca.xbf = xbf; ca.hbf = hbf;
    ca.qb = qb; ca.kvb = kvb; ca.A2 = A2;
    ca.row_ptr = row_ptr; ca.epk = epk;
    ca.Wt5 = Wt5; ca.bias5 = bias5; ca.sc5 = sc5;
    ca.Wto = Wto; ca.out_b = out_b;
    ca.skip = skip; ca.ln_g = ln_g; ca.ln_b = ln_b;
    ca.x = x; ca.hA = hA; ca.hB = hB; ca.outp = outp;
    void* kargs[] = { (void*)&ca };
    hipLaunchCooperativeKernel(layers_k, dim3(coop_blocks), dim3(256), kargs, 0, stream);
}

// Round 5
// 473.736 us; speedup vs baseline: 5.1443x; 5.1443x over previous
//
#include <hip/hip_runtime.h>
#include <math.h>

#define NN 20000
#define NPAD 20096          // padded rows for unguarded MFMA staging (157*128)
#define CC 256
#define HH 8
#define EE 160000
#define TE 320000
#define KVSTRIDE 512        // bytes per kv row: interleaved per-lane [k 8B | v 8B] x 32
#define APAN ((size_t)NPAD*32)   // u16 elems per A-operand k-panel (xbf/hbf/A2)
#define BPAN 40960               // u16 elems per Wt5 k-panel (1280*32)
#define OPAN 8192                // u16 elems per Wto k-panel (256*32)

typedef unsigned short u16;
typedef unsigned char u8;
typedef __attribute__((ext_vector_type(8))) short bf16x8;
typedef __attribute__((ext_vector_type(4))) float f32x4;
typedef __attribute__((ext_vector_type(2))) float f32x2;

__device__ __forceinline__ float gelu_exact(float x){
    return 0.5f*x*(1.0f+erff(x*0.7071067811865476f));
}
__device__ __forceinline__ u16 f2bf(float f){
    unsigned u = __float_as_uint(f);
    unsigned r = (u + 0x7fffu + ((u >> 16) & 1u)) >> 16;
    return (u16)r;
}
__device__ __forceinline__ void dec8(uint4 u, float* f){
    f[0]=__uint_as_float(u.x<<16); f[1]=__uint_as_float(u.x&0xffff0000u);
    f[2]=__uint_as_float(u.y<<16); f[3]=__uint_as_float(u.y&0xffff0000u);
    f[4]=__uint_as_float(u.z<<16); f[5]=__uint_as_float(u.z&0xffff0000u);
    f[6]=__uint_as_float(u.w<<16); f[7]=__uint_as_float(u.w&0xffff0000u);
}
__device__ __forceinline__ void dec8_fp8u(unsigned lo, unsigned hi, float* f){
    f32x2 a = __builtin_amdgcn_cvt_pk_f32_fp8(lo, false);
    f32x2 b = __builtin_amdgcn_cvt_pk_f32_fp8(lo, true);
    f32x2 c = __builtin_amdgcn_cvt_pk_f32_fp8(hi, false);
    f32x2 d = __builtin_amdgcn_cvt_pk_f32_fp8(hi, true);
    f[0]=a.x; f[1]=a.y; f[2]=b.x; f[3]=b.y;
    f[4]=c.x; f[5]=c.y; f[6]=d.x; f[7]=d.y;
}
__device__ __forceinline__ uint2 enc8_fp8(const float* f){
    int t0 = __builtin_amdgcn_cvt_pk_fp8_f32(f[0], f[1], 0, false);
    t0     = __builtin_amdgcn_cvt_pk_fp8_f32(f[2], f[3], t0, true);
    int t1 = __builtin_amdgcn_cvt_pk_fp8_f32(f[4], f[5], 0, false);
    t1     = __builtin_amdgcn_cvt_pk_fp8_f32(f[6], f[7], t1, true);
    uint2 r; r.x = (unsigned)t0; r.y = (unsigned)t1;
    return r;
}
__device__ __forceinline__ float dot8(const float* a, const float* b){
    return a[0]*b[0]+a[1]*b[1]+a[2]*b[2]+a[3]*b[3]
          +a[4]*b[4]+a[5]*b[5]+a[6]*b[6]+a[7]*b[7];
}
__device__ __forceinline__ void gload_lds16(const u16* gsrc, u16* lds_dst){
    __builtin_amdgcn_global_load_lds((const __attribute__((address_space(1))) unsigned int*)gsrc,
                                     (__attribute__((address_space(3))) unsigned int*)lds_dst,
                                     16, 0, 0);
}

// ======================= CSR build =======================
__global__ void hist_k(const int* __restrict__ ei0, const int* __restrict__ ei1,
                       int* __restrict__ cnt){
    int e = blockIdx.x*256 + threadIdx.x;
    if (e < TE){
        int dst = (e < EE) ? ei0[EE + e] : ei1[EE + (e - EE)];
        atomicAdd(&cnt[dst], 1);
    }
}
// merged scan+finalize: each block recomputes its global prefix from cnt directly
// (20K extra reads total — trivial), then scans its own 256 and emits row_ptr.
__global__ void rowptr_k(const int* __restrict__ cnt, int* __restrict__ row_ptr){
    __shared__ int tmp[256];
    __shared__ int pre_s;
    int tid = threadIdx.x, b = blockIdx.x;
    int s = 0;
    for (int j = tid; j < b*256; j += 256) s += cnt[j];
    tmp[tid] = s;
    __syncthreads();
    for (int d=128; d>0; d>>=1){
        if (tid < d) tmp[tid] += tmp[tid+d];
        __syncthreads();
    }
    if (tid == 0) pre_s = tmp[0];
    __syncthreads();
    int i = b*256 + tid;
    int v = (i < NN) ? cnt[i] : 0;
    tmp[tid] = v;
    __syncthreads();
    for (int d=1; d<256; d<<=1){
        int t = (tid>=d) ? tmp[tid-d] : 0;
        __syncthreads();
        tmp[tid] += t;
        __syncthreads();
    }
    if (i < NN) row_ptr[i] = tmp[tid] - v + pre_s;     // exclusive prefix
    if (i == NN) row_ptr[NN] = TE;
}
// stores the final kv-row index rel*NN+src per CSR slot
__global__ void scatter_k(const int* __restrict__ ei0, const int* __restrict__ ei1,
                          const int* __restrict__ row_ptr, int* __restrict__ cursor,
                          int* __restrict__ epk){
    int e = blockIdx.x*256 + threadIdx.x;
    if (e < TE){
        int src, dst, rel;
        if (e < EE){ src = ei0[e]; dst = ei0[EE+e]; rel = 0; }
        else { int ee=e-EE; src = ei1[ee]; dst = ei1[EE+ee]; rel = 1; }
        int pos = atomicAdd(&cursor[dst], 1);
        epk[row_ptr[dst] + pos] = rel*NN + src;
    }
}

// ======================= fused weight/input prep (one dispatch) =======================
// blocks [0,1024): Wt5 q-copy; [1024,1536): Wt5 rel-fold (8 f-outputs/thread, W-row
// reuse + float4 Rm loads — accumulation order over d unchanged -> bit-identical);
// [1536,4036): cvt x->xbf; [4036,5060): Wto; [5060,5080): bias5+sc5;
// [5080,5120): zero cnt+cursor (replaces memset dispatch).
// sc5 for k-outputs folds prel/sqrt(DH) * log2(e): attention runs in log2 domain.
__global__ void prep_k(const float* __restrict__ kqv_w, const float* __restrict__ kqv_b,
                       const float* __restrict__ krel, const float* __restrict__ vrel,
                       const float* __restrict__ prel, const float* __restrict__ out_w,
                       const float* __restrict__ x,
                       u16* __restrict__ Wt, u16* __restrict__ xbf, u16* __restrict__ Wto,
                       float* __restrict__ bias5, float* __restrict__ sc5,
                       int* __restrict__ cnt, int* __restrict__ cursor){
    int b = blockIdx.x;
    if (b < 1024){
        // q columns: straight copy-transpose
        int idx = b*256 + threadIdx.x;                 // 4l * 256n * 256k
        int k = idx & 255;
        int n = (idx >> 8) & 255;
        int l = idx >> 16;
        const float* W = kqv_w + (size_t)l*196608;     // [256][768]
        Wt[(size_t)l*327680 + (size_t)(k>>5)*BPAN + n*32 + (k&31)] = f2bf(W[k*768 + 256 + n]);
    } else if (b < 1536){
        // rel-folded k/v columns: 8 outputs per thread (f-octet)
        int idx = (b-1024)*256 + threadIdx.x;          // 131072 threads
        int k  = idx & 255;
        int q8 = (idx >> 8) & 3;                       // f-octet: f = q8*8 + j
        int h  = (idx >> 10) & 7;
        int g  = (idx >> 13) & 3;
        int l  = idx >> 15;
        int r = g & 1, isv = g >> 1;
        const float* W = kqv_w + (size_t)l*196608;
        const float* Rm = (isv ? vrel : krel) + ((size_t)l*2 + r)*8192 + h*1024;
        int base = isv ? 512 : 0;
        const float4* Wr = (const float4*)(W + k*768 + base + h*32);
        int f0 = q8*8;
        float a0=0.f,a1=0.f,a2=0.f,a3=0.f,a4=0.f,a5=0.f,a6=0.f,a7=0.f;
        #pragma unroll
        for (int d4=0; d4<8; ++d4){
            float4 wv = Wr[d4];
            #pragma unroll
            for (int dd=0; dd<4; ++dd){
                int d = d4*4 + dd;
                float wd = (dd==0)?wv.x:((dd==1)?wv.y:((dd==2)?wv.z:wv.w));
                const float4* RmR = (const float4*)(Rm + d*32 + f0);
                float4 r0 = RmR[0], r1 = RmR[1];
                a0 += wd*r0.x; a1 += wd*r0.y; a2 += wd*r0.z; a3 += wd*r0.w;
                a4 += wd*r1.x; a5 += wd*r1.y; a6 += wd*r1.z; a7 += wd*r1.w;
            }
        }
        float av[8] = {a0,a1,a2,a3,a4,a5,a6,a7};
        size_t wbase = (size_t)l*327680 + (size_t)(k>>5)*BPAN + (size_t)(k&31);
        int n0 = 256 + g*256 + h*32 + f0;
        #pragma unroll
        for (int j=0;j<8;++j)
            Wt[wbase + (size_t)(n0+j)*32] = f2bf(av[j]);
    } else if (b < 4036){
        int idx = (b-1536)*256 + threadIdx.x;          // 640000 (8 elems each)
        int e = idx*8;
        int row = e >> 8, col = e & 255;
        const float4* xp = (const float4*)x;
        float4 a = xp[(size_t)idx*2], bb = xp[(size_t)idx*2+1];
        uint4 o;
        o.x = (unsigned)f2bf(a.x) | ((unsigned)f2bf(a.y)<<16);
        o.y = (unsigned)f2bf(a.z) | ((unsigned)f2bf(a.w)<<16);
        o.z = (unsigned)f2bf(bb.x) | ((unsigned)f2bf(bb.y)<<16);
        o.w = (unsigned)f2bf(bb.z) | ((unsigned)f2bf(bb.w)<<16);
        *(uint4*)&xbf[(size_t)(col>>5)*APAN + (size_t)row*32 + (col&31)] = o;
    } else if (b < 5060){
        int idx = (b-4036)*256 + threadIdx.x;          // 4*256*256
        int k = idx & 255;
        int n = (idx >> 8) & 255;
        int l = idx >> 16;
        Wto[(size_t)l*65536 + (size_t)(k>>5)*OPAN + n*32 + (k&31)] =
            f2bf(out_w[(size_t)l*65536 + k*256 + n]);
    } else if (b < 5080){
        int idx = (b-5060)*256 + threadIdx.x;          // 4*1280
        if (idx >= 4*1280) return;
        int n = idx % 1280, l = idx / 1280;
        const float* B = kqv_b + l*768;
        float val, scl = 1.f;
        if (n < 256) val = B[256+n];
        else {
            int g = (n-256) >> 8;
            int r = g & 1, isv = g >> 1;
            int c = (n-256) & 255;
            int h = c >> 5, f = c & 31;
            const float* Rm = (isv ? vrel : krel) + ((size_t)l*2 + r)*8192 + h*1024;
            int base = isv ? 512 : 0;
            float a = 0.f;
            for (int d=0; d<32; ++d) a += B[base + h*32 + d] * Rm[d*32 + f];
            val = a;
            // prel / sqrt(DH) * log2(e): logits computed in log2 domain downstream
            if (!isv) scl = prel[l*16 + r*8 + h] * (0.17677669529663687f * 1.4426950408889634f);
        }
        bias5[idx] = val;
        sc5[idx] = scl;
    } else {
        // zero cnt + cursor (replaces hipMemsetAsync dispatch)
        int t = (b-5080)*256 + threadIdx.x;            // [0,10240)
        for (int j = t; j < NN; j += 10240){ cnt[j] = 0; cursor[j] = 0; }
    }
}

// ======================= K1: 5-output MFMA GEMM (pipelined dbuf, XCD-clustered) =========
// T3 minimum 2-phase: stage panel t+1 (global_load_lds) BEFORE computing panel t,
// single __syncthreads per panel.
// LDS: As dbuf 16KB + Bs dbuf 16KB; Cs (33.8KB) aliases both post-K-loop.
__global__ __launch_bounds__(256) void gemm5_k(const u16* __restrict__ A,
        const u16* __restrict__ Wt, const float* __restrict__ biasp,
        const float* __restrict__ sc5p,
        u16* __restrict__ qb, u8* __restrict__ kvb){
    int L = blockIdx.x;
    int xcd = L & 7;
    int t = L >> 3;                  // 0..199
    int ytile = xcd*20 + t/10;       // 0..159
    int xtile = t % 10;
    if (ytile >= 157) return;        // uniform per block (before any barrier)
    int col0 = xtile * 128;
    int row0 = ytile * 128;

    __shared__ __align__(16) char smem[33792];   // max(As+Bs dbuf=32K, Cs=128*66*4)
    u16* As = (u16*)smem;                        // 2 buffers of 4096 u16
    u16* Bs = (u16*)(smem + 16384);              // 2 buffers of 4096 u16
    float* Cs = (float*)smem;                    // 128*66 (aliases As/Bs post-K-loop)
    int tid = threadIdx.x;
    int w = tid >> 6, lane = tid & 63;
    int wm = w & 1, wn = w >> 1;
    f32x4 acc[4][4];
    #pragma unroll
    for (int i=0;i<4;++i)
        #pragma unroll
        for (int j=0;j<4;++j) acc[i][j] = (f32x4){0.f,0.f,0.f,0.f};

    int lm = lane & 15, quad = lane >> 4;
    int kq0 = quad ^ (lm & 3);
    int aoff = (wm*64 + lm)*32 + kq0*8;
    int boff = (wn*64 + lm)*32 + kq0*8;

    auto stage5 = [&](int pan, int buf){
        #pragma unroll
        for (int it = 0; it < 2; ++it){
            int s = it*256 + tid;              // 16B slot id (0..511)
            int row = s >> 2, q0 = s & 3;
            int kq = q0 ^ (row & 3);           // write-side swizzle via source addr
            gload_lds16(&A [(size_t)pan*APAN + (size_t)(row0+row)*32 + kq*8],
                        &As[(size_t)buf*4096 + (size_t)s*8]);
            gload_lds16(&Wt[(size_t)pan*BPAN + (size_t)(col0+row)*32 + kq*8],
                        &Bs[(size_t)buf*4096 + (size_t)s*8]);
        }
    };

    stage5(0, 0);
    __syncthreads();
    #pragma unroll
    for (int pan = 0; pan < 8; ++pan){
        int cur = pan & 1;
        if (pan < 7) stage5(pan+1, cur^1);     // in flight across the compute below
        bf16x8 af[4], bfr[4];
        #pragma unroll
        for (int mi=0; mi<4; ++mi) af[mi]  = *(bf16x8*)&As[cur*4096 + aoff + mi*512];
        #pragma unroll
        for (int ni=0; ni<4; ++ni) bfr[ni] = *(bf16x8*)&Bs[cur*4096 + boff + ni*512];
        #pragma unroll
        for (int mi=0; mi<4; ++mi)
            #pragma unroll
            for (int ni=0; ni<4; ++ni)
                acc[mi][ni] = __builtin_amdgcn_mfma_f32_16x16x32_bf16(af[mi], bfr[ni], acc[mi][ni], 0,0,0);
        __syncthreads();    // drains vmcnt(0); also fences Cs aliasing after last pan
    }

    int bufi = col0 >> 8;   // 0:q 1:kr0 2:kr1 3:vr0 4:vr1 (uniform per block)
    int cbase = col0 & 255;
    float bvv[4], scv[4];
    #pragma unroll
    for (int ni=0; ni<4; ++ni){
        bvv[ni] = biasp[col0 + wn*64 + ni*16 + lm];
        scv[ni] = sc5p [col0 + wn*64 + ni*16 + lm];
    }

    int rowl_s = tid >> 3;              // 0..31
    int col8   = tid & 7;               // 0..7 (8 lcols each)
    int gcb    = (col8 >> 2)*64 + (col8 & 3)*8;

    #pragma unroll
    for (int p=0; p<2; ++p){
        if (p) __syncthreads();
        #pragma unroll
        for (int nj=0; nj<2; ++nj){
            int ni = p*2 + nj;
            int lcol = wn*32 + nj*16 + lm;
            #pragma unroll
            for (int mi=0; mi<4; ++mi){
                #pragma unroll
                for (int t2=0; t2<4; ++t2){
                    int lr = wm*64 + mi*16 + quad*4 + t2;
                    Cs[lr*66 + lcol] = (acc[mi][ni][t2] + bvv[ni]) * scv[ni];
                }
            }
        }
        __syncthreads();
        int cw = cbase + gcb + p*32;
        #pragma unroll
        for (int it=0; it<4; ++it){
            int rl = rowl_s + it*32;
            int r = row0 + rl;
            if (r < NN){
                const float* src = &Cs[rl*66 + col8*8];
                float cf[8];
                *(float4*)&cf[0] = *(const float4*)&src[0];
                *(float4*)&cf[4] = *(const float4*)&src[4];
                if (bufi == 0){
                    uint4 o;
                    o.x = (unsigned)f2bf(cf[0]) | ((unsigned)f2bf(cf[1])<<16);
                    o.y = (unsigned)f2bf(cf[2]) | ((unsigned)f2bf(cf[3])<<16);
                    o.z = (unsigned)f2bf(cf[4]) | ((unsigned)f2bf(cf[5])<<16);
                    o.w = (unsigned)f2bf(cf[6]) | ((unsigned)f2bf(cf[7])<<16);
                    *(uint4*)&qb[(size_t)r*256 + cw] = o;
                } else if (bufi <= 2){
                    // k-part: interleaved layout, lane slot = (cw>>3)*16
                    int rel = bufi - 1;
                    uint2 o = enc8_fp8(cf);
                    *(uint2*)&kvb[(size_t)(rel*NN + r)*KVSTRIDE + (size_t)cw*2] = o;
                } else {
                    // v-part: 8 bytes after the matching k slot
                    int rel = bufi - 3;
                    uint2 o = enc8_fp8(cf);
                    *(uint2*)&kvb[(size_t)(rel*NN + r)*KVSTRIDE + (size_t)cw*2 + 8] = o;
                }
            }
        }
    }
}

// ======================= K2: split-wave CSR attention, online softmax ==============
// kv row interleaved per lane: [k 8B | v 8B] x 32 -> ONE uint4 gather per edge.
// Pair-processed online softmax (2 edges per iteration per half) in log2 domain.
// A2 output in k-panel layout (A operand of gemmOln/gemmO)
__global__ __launch_bounds__(256) void attn_k(const u16* __restrict__ qb,
        const u8* __restrict__ kvb,
        const int* __restrict__ row_ptr, const int* __restrict__ epk,
        u16* __restrict__ A2){
    int wv = threadIdx.x >> 6, lane = threadIdx.x & 63;
    int node = blockIdx.x*4 + wv;
    int l32 = lane & 31;
    int half = lane >> 5;
    int start = row_ptr[node], end = row_ptr[node+1];
    float qf[8];
    {
        uint4 qr = *(const uint4*)&qb[(size_t)node*256 + l32*8];
        dec8(qr, qf);
    }
    float m = -1e30f, s = 0.f;
    float acc[8] = {0.f,0.f,0.f,0.f,0.f,0.f,0.f,0.f};

    // this half's edges: i0, i0+2, i0+4, ...  (stride 2); 2 consumed per iteration
    int i0 = start + half;
    uint4 kv0 = {0,0,0,0}, kv1 = {0,0,0,0}, kv2 = {0,0,0,0}, kv3 = {0,0,0,0};
    if (i0     < end) kv0 = *(const uint4*)(&kvb[(size_t)epk[i0  ]*KVSTRIDE] + l32*16);
    if (i0 + 2 < end) kv1 = *(const uint4*)(&kvb[(size_t)epk[i0+2]*KVSTRIDE] + l32*16);
    if (i0 + 4 < end) kv2 = *(const uint4*)(&kvb[(size_t)epk[i0+4]*KVSTRIDE] + l32*16);
    if (i0 + 6 < end) kv3 = *(const uint4*)(&kvb[(size_t)epk[i0+6]*KVSTRIDE] + l32*16);
    int pk0 = (i0 + 8  < end) ? epk[i0+8]  : 0;
    int pk1 = (i0 + 10 < end) ? epk[i0+10] : 0;

    for (int i = i0; i < end; i += 4){
        uint4 ca = kv0, cb = kv1;
        kv0 = kv2; kv1 = kv3;
        if (i + 8  < end) kv2 = *(const uint4*)(&kvb[(size_t)pk0*KVSTRIDE] + l32*16);
        if (i + 10 < end) kv3 = *(const uint4*)(&kvb[(size_t)pk1*KVSTRIDE] + l32*16);
        if (i + 12 < end) pk0 = epk[i+12];
        if (i + 14 < end) pk1 = epk[i+14];

        float kfa[8], kfb[8];
        dec8_fp8u(ca.x, ca.y, kfa);
        dec8_fp8u(cb.x, cb.y, kfb);
        float p0 = dot8(qf, kfa);
        float p1 = dot8(qf, kfb);
        p0 += __shfl_xor(p0, 1);  p1 += __shfl_xor(p1, 1);
        p0 += __shfl_xor(p0, 2);  p1 += __shfl_xor(p1, 2);   // per-head log2-logit
        if (i + 2 >= end) p1 = -1e30f;                       // second slot invalid
        float mo = m;
        m = fmaxf(fmaxf(m, p0), p1);                         // v_max3
        float sc  = __builtin_amdgcn_exp2f(mo - m);
        float pe0 = __builtin_amdgcn_exp2f(p0 - m);
        float pe1 = __builtin_amdgcn_exp2f(p1 - m);
        s = s*sc + (pe0 + pe1);
        float va[8], vb[8];
        dec8_fp8u(ca.z, ca.w, va);
        dec8_fp8u(cb.z, cb.w, vb);
        #pragma unroll
        for (int j=0;j<8;++j) acc[j] = acc[j]*sc + (pe0*va[j] + pe1*vb[j]);
    }
    // merge the two halves' online-softmax states (m=-1e30: no inf-inf NaN)
    float mO = __shfl_xor(m, 32);
    float mA = fmaxf(m, mO);
    float eS = __builtin_amdgcn_exp2f(m - mA);
    float sh = s * eS;
    float sA = sh + __shfl_xor(sh, 32);
    float rs = 1.f / fmaxf(sA, 1e-16f);
    float oA[8];
    #pragma unroll
    for (int j=0;j<8;++j){
        float a = acc[j] * eS;
        oA[j] = a + __shfl_xor(a, 32);
    }
    if (half == 0){
        u16 o[8];
        #pragma unroll
        for (int j=0;j<8;++j) o[j] = f2bf(gelu_exact(oA[j]*rs));
        uint4 ov;
        ov.x = (unsigned)o[0] | ((unsigned)o[1]<<16);
        ov.y = (unsigned)o[2] | ((unsigned)o[3]<<16);
        ov.z = (unsigned)o[4] | ((unsigned)o[5]<<16);
        ov.w = (unsigned)o[6] | ((unsigned)o[7]<<16);
        int c0 = l32*8;
        *(uint4*)&A2[(size_t)(c0>>5)*APAN + (size_t)node*32 + (c0&31)] = ov;
    }
}

// ======================= K3a: out GEMM + skip + relu + LN (layers 0-2) ===========
// A2 and Wto in k-panel layout; pipelined dbuf staging (same T3 structure as gemm5).
// emits h_out fp32 (row-major) and hbf bf16 k-panels for next gemm5
__global__ __launch_bounds__(256) void gemmOln_k(const u16* __restrict__ A,
        const u16* __restrict__ Wt, const float* __restrict__ bias,
        const float* __restrict__ h_in, const float* __restrict__ skip_l,
        const float* __restrict__ g, const float* __restrict__ b,
        float* __restrict__ h_out, u16* __restrict__ hbf){
    __shared__ u16 As[4096];          // 2 buffers x (64 rows x 32 k)
    __shared__ u16 Bs[16384];         // 2 buffers x (256 cols x 32 k)
    __shared__ float part_s[64*33];
    __shared__ float part_q[64*33];
    __shared__ float mu_s[64], rstd_s[64];
    int tid = threadIdx.x;
    int w = tid >> 6, lane = tid & 63;
    int row0 = blockIdx.x * 64;
    int wm = w & 1, wn = w >> 1;
    f32x4 acc[2][8];
    #pragma unroll
    for (int i=0;i<2;++i)
        #pragma unroll
        for (int j=0;j<8;++j) acc[i][j] = (f32x4){0.f,0.f,0.f,0.f};

    int lm = lane & 15, quad = lane >> 4;
    int kq0 = quad ^ (lm & 3);
    int aoff = (wm*32 + lm)*32 + kq0*8;
    int boff = (wn*128 + lm)*32 + kq0*8;

    auto stageO = [&](int kk, int buf){
        {
            int s = tid;                       // 256 slots = 64 rows x 4
            int row = s >> 2, q0 = s & 3;
            int kq = q0 ^ (row & 3);
            gload_lds16(&A[(size_t)kk*APAN + (size_t)(row0+row)*32 + kq*8],
                        &As[(size_t)buf*2048 + (size_t)(w*64)*8]);
        }
        #pragma unroll
        for (int it = 0; it < 4; ++it){        // 1024 slots = 256 n-rows x 4
            int s = it*256 + tid;
            int row = s >> 2, q0 = s & 3;
            int kq = q0 ^ (row & 3);
            gload_lds16(&Wt[(size_t)kk*OPAN + (size_t)row*32 + kq*8],
                        &Bs[(size_t)buf*8192 + (size_t)s*8]);
        }
    };

    stageO(0, 0);
    __syncthreads();
    #pragma unroll
    for (int kk = 0; kk < 8; ++kk){
        int cur = kk & 1;
        if (kk < 7) stageO(kk+1, cur^1);
        bf16x8 af[2], bfr[8];
        #pragma unroll
        for (int mi=0; mi<2; ++mi) af[mi]  = *(bf16x8*)&As[cur*2048 + aoff + mi*512];
        #pragma unroll
        for (int ni=0; ni<8; ++ni) bfr[ni] = *(bf16x8*)&Bs[cur*8192 + boff + ni*512];
        #pragma unroll
        for (int mi=0; mi<2; ++mi)
            #pragma unroll
            for (int ni=0; ni<8; ++ni)
                acc[mi][ni] = __builtin_amdgcn_mfma_f32_16x16x32_bf16(af[mi], bfr[ni], acc[mi][ni], 0,0,0);
        __syncthreads();
    }

    float sskip = 1.f/(1.f+__expf(-skip_l[0]));
    float osk = 1.f - sskip;
    float bv[8], gv[8], bbv[8];
    #pragma unroll
    for (int ni=0; ni<8; ++ni){
        int colg = wn*128 + ni*16 + lm;
        bv[ni]  = bias[colg];
        gv[ni]  = g[colg];
        bbv[ni] = b[colg];
    }
    #pragma unroll
    for (int mi=0; mi<2; ++mi){
        #pragma unroll
        for (int t=0; t<4; ++t){
            int lr = wm*32 + mi*16 + quad*4 + t;
            int r = row0 + lr;
            float ps = 0.f, pq = 0.f;
            #pragma unroll
            for (int ni=0; ni<8; ++ni){
                int colg = wn*128 + ni*16 + lm;
                float hv = (r < NN) ? h_in[(size_t)r*256 + colg] : 0.f;
                float val = sskip*(acc[mi][ni][t] + bv[ni]) + osk*hv;
                val = fmaxf(val, 0.f);
                acc[mi][ni][t] = val;
                ps += val; pq += val*val;
            }
            part_s[lr*33 + wn*16 + lm] = ps;
            part_q[lr*33 + wn*16 + lm] = pq;
        }
    }
    __syncthreads();
    if (tid < 64){
        float S = 0.f, Q = 0.f;
        #pragma unroll 8
        for (int t2=0; t2<32; ++t2){
            S += part_s[tid*33 + t2];
            Q += part_q[tid*33 + t2];
        }
        float mu = S * (1.f/256.f);
        float var = Q * (1.f/256.f) - mu*mu;
        mu_s[tid] = mu;
        rstd_s[tid] = rsqrtf(var + 1e-5f);
    }
    __syncthreads();
    #pragma unroll
    for (int mi=0; mi<2; ++mi){
        #pragma unroll
        for (int t=0; t<4; ++t){
            int lr = wm*32 + mi*16 + quad*4 + t;
            int r = row0 + lr;
            if (r >= NN) continue;
            float mu = mu_s[lr], rstd = rstd_s[lr];
            #pragma unroll
            for (int ni=0; ni<8; ++ni){
                int colg = wn*128 + ni*16 + lm;
                float o = (acc[mi][ni][t] - mu)*rstd*gv[ni] + bbv[ni];
                h_out[(size_t)r*256 + colg] = o;
                hbf[(size_t)(colg>>5)*APAN + (size_t)r*32 + (colg&31)] = f2bf(o);
            }
        }
    }
}

// ======================= K3b: out GEMM + skip blend (final layer) =======================
// A2 and Wto in k-panel layout; pipelined dbuf staging
__global__ __launch_bounds__(256) void gemmO_k(const u16* __restrict__ A,
        const u16* __restrict__ Wt, const float* __restrict__ bias,
        const float* __restrict__ h_in, const float* __restrict__ skip_l,
        float* __restrict__ outp){
    __shared__ u16 As[8192];          // 2 buffers x 4096
    __shared__ u16 Bs[8192];          // 2 buffers x 4096
    int tid = threadIdx.x;
    int w = tid >> 6, lane = tid & 63;
    int row0 = blockIdx.x * 128;
    int col0 = blockIdx.y * 128;
    int wm = w & 1, wn = w >> 1;
    f32x4 acc[4][4];
    #pragma unroll
    for (int i=0;i<4;++i)
        #pragma unroll
        for (int j=0;j<4;++j) acc[i][j] = (f32x4){0.f,0.f,0.f,0.f};

    int lm = lane & 15, quad = lane >> 4;
    int kq0 = quad ^ (lm & 3);
    int aoff = (wm*64 + lm)*32 + kq0*8;
    int boff = (wn*64 + lm)*32 + kq0*8;

    auto stageF = [&](int kk, int buf){
        #pragma unroll
        for (int it = 0; it < 2; ++it){
            int s = it*256 + tid;
            int row = s >> 2, q0 = s & 3;
            int kq = q0 ^ (row & 3);
            gload_lds16(&A [(size_t)kk*APAN + (size_t)(row0+row)*32 + kq*8],
                        &As[(size_t)buf*4096 + (size_t)s*8]);
            gload_lds16(&Wt[(size_t)kk*OPAN + (size_t)(col0+row)*32 + kq*8],
                        &Bs[(size_t)buf*4096 + (size_t)s*8]);
        }
    };

    stageF(0, 0);
    __syncthreads();
    #pragma unroll
    for (int kk = 0; kk < 8; ++kk){
        int cur = kk & 1;
        if (kk < 7) stageF(kk+1, cur^1);
        bf16x8 af[4], bfr[4];
        #pragma unroll
        for (int mi=0; mi<4; ++mi) af[mi]  = *(bf16x8*)&As[cur*4096 + aoff + mi*512];
        #pragma unroll
        for (int ni=0; ni<4; ++ni) bfr[ni] = *(bf16x8*)&Bs[cur*4096 + boff + ni*512];
        #pragma unroll
        for (int mi=0; mi<4; ++mi)
            #pragma unroll
            for (int ni=0; ni<4; ++ni)
                acc[mi][ni] = __builtin_amdgcn_mfma_f32_16x16x32_bf16(af[mi], bfr[ni], acc[mi][ni], 0,0,0);
        __syncthreads();
    }
    float s = 1.f/(1.f+expf(-skip_l[0]));
    float os = 1.f - s;
    #pragma unroll
    for (int ni=0; ni<4; ++ni){
        int colg = col0 + wn*64 + ni*16 + lm;
        float bv = bias[colg];
        #pragma unroll
        for (int mi=0; mi<4; ++mi){
            #pragma unroll
            for (int t=0; t<4; ++t){
                int r = row0 + wm*64 + mi*16 + quad*4 + t;
                if (r < NN)
                    outp[(size_t)r*256 + colg] =
                        s*(acc[mi][ni][t] + bv) + os*h_in[(size_t)r*256 + colg];
            }
        }
    }
}

// ======================= host =======================
extern "C" void kernel_launch(void* const* d_in, const int* in_sizes, int n_in,
                              void* d_out, int out_size, void* d_ws, size_t ws_size,
                              hipStream_t stream){
    (void)in_sizes; (void)n_in; (void)out_size; (void)ws_size;
    const float* x     = (const float*)d_in[0];
    const int*   ei0   = (const int*)d_in[1];
    const int*   ei1   = (const int*)d_in[2];
    const float* kqv_w = (const float*)d_in[3];
    const float* kqv_b = (const float*)d_in[4];
    const float* out_w = (const float*)d_in[5];
    const float* out_b = (const float*)d_in[6];
    const float* skip  = (const float*)d_in[7];
    const float* krel  = (const float*)d_in[8];
    const float* vrel  = (const float*)d_in[9];
    const float* prel  = (const float*)d_in[10];
    const float* ln_g  = (const float*)d_in[11];
    const float* ln_b  = (const float*)d_in[12];
    float* outp = (float*)d_out;

    char* wp = (char*)d_ws;
    auto alloc = [&](size_t bytes)->void*{
        void* p = wp; wp += (bytes + 255) & ~(size_t)255; return p;
    };
    float* hA    = (float*)alloc((size_t)NN*CC*4);
    float* hB    = (float*)alloc((size_t)NN*CC*4);
    u16*   xbf   = (u16*)alloc((size_t)NPAD*CC*2);   // k-panel layout
    u16*   hbf   = (u16*)alloc((size_t)NPAD*CC*2);   // k-panel layout
    u16*   A2    = (u16*)alloc((size_t)NPAD*CC*2);   // k-panel layout
    u16*   qb    = (u16*)alloc((size_t)NN*CC*2);
    u8*    kvb   = (u8*)alloc((size_t)2*NN*KVSTRIDE);   // [rel*NN+node][lane-interleaved k|v fp8]
    u16*   Wt5   = (u16*)alloc((size_t)4*1280*256*2);   // k-panel layout
    u16*   Wto   = (u16*)alloc((size_t)4*256*256*2);    // k-panel layout
    float* bias5 = (float*)alloc((size_t)4*1280*4);
    float* sc5   = (float*)alloc((size_t)4*1280*4);
    int* cnt     = (int*)alloc((size_t)NN*4);
    int* cursor  = (int*)alloc((size_t)NN*4);
    int* row_ptr = (int*)alloc((size_t)(NN+1)*4);
    int* epk     = (int*)alloc((size_t)TE*4);

    // fused prep (weights + input cast + cnt/cursor zeroing) — one dispatch
    prep_k<<<5120,256,0,stream>>>(kqv_w, kqv_b, krel, vrel, prel, out_w, x,
                                  Wt5, xbf, Wto, bias5, sc5, cnt, cursor);

    // CSR build (3 dispatches: hist -> rowptr -> scatter)
    hist_k<<<1250,256,0,stream>>>(ei0, ei1, cnt);
    rowptr_k<<<79,256,0,stream>>>(cnt, row_ptr);
    scatter_k<<<1250,256,0,stream>>>(ei0, ei1, row_ptr, cursor, epk);

    const float* h_in = x;
    const u16*   Ain  = xbf;
    float* houts[4] = {hA, hB, hA, outp};
    for (int l=0; l<4; ++l){
        gemm5_k<<<1600,256,0,stream>>>(Ain, Wt5 + (size_t)l*327680,
                bias5 + l*1280, sc5 + l*1280, qb, kvb);
        attn_k<<<5000,256,0,stream>>>(qb, kvb, row_ptr, epk, A2);
        if (l < 3){
            gemmOln_k<<<314,256,0,stream>>>(A2, Wto + (size_t)l*65536,
                    out_b + l*256, h_in, skip + l, ln_g + l*256, ln_b + l*256,
                    houts[l], hbf);
        } else {
            gemmO_k<<<dim3(157,2),256,0,stream>>>(A2, Wto + (size_t)l*65536,
                    out_b + l*256, h_in, skip + l, outp);
        }
        h_in = houts[l];
        Ain = hbf;
    }
}